// Round 10
// baseline (132.437 us; speedup 1.0000x reference)
//
#include <hip/hip_runtime.h>
#include <hip/hip_bf16.h>

#define B_ 2
#define H_ 16
#define S_ 2048
#define D_ 64
#define BQ 64      // q-rows per block; 2 teams x 2 waves x 32 rows, split-K in-tile
#define BK 64
#define LDSTR 72   // K/V row stride 144B: 16B-aligned, odd bank-quad spread
#define PSTR 40    // P row stride: 32 keys + 8 pad (16B-aligned b128 reads)
#define LOG2E 1.4426950408889634f
#define FIXM 10.0f // fixed softmax shift: p = e^logit * 2^-FIXM (GLOBAL scale ->
                   // team partials over disjoint key sets sum with NO rescale)

#if __has_builtin(__builtin_amdgcn_exp2f)
#define EXP2F(x) __builtin_amdgcn_exp2f(x)
#else
#define EXP2F(x) __expf((x) * 0.6931471805599453f)
#endif

typedef _Float16 half8 __attribute__((ext_vector_type(8)));
typedef _Float16 half4 __attribute__((ext_vector_type(4)));
typedef __fp16   fp16x2 __attribute__((ext_vector_type(2)));
typedef float floatx4 __attribute__((ext_vector_type(4)));

__global__ __launch_bounds__(256, 3)   // 3 waves/SIMD -> VGPR cap ~170: no spills
void t5_attn_kernel(const float* __restrict__ qg_, const float* __restrict__ kg_,
                    const float* __restrict__ vg_, const float* __restrict__ bt,
                    const int* __restrict__ elen, float* __restrict__ outg_)
{
    // dbuf K/V (shared by both teams) + slim per-wave P + lut = 47 KB -> 3 blocks/CU
    __shared__ __align__(16) _Float16 Kl[2][BK][LDSTR];  // [buf][key][dim]
    __shared__ __align__(16) _Float16 Vt[2][D_][LDSTR];  // [buf][dim][key]
    __shared__ __align__(16) _Float16 Pp[4][32][PSTR];   // per-wave P [qrow][key32]
    __shared__ float lut[256];                           // bias*log2e - FIXM

    // 1D grid, batch interleaved in bit 0 (keeps the R6 FETCH/L3 win)
    const int bx   = blockIdx.x;
    const int b    = bx & 1;
    const int h    = (bx >> 1) & 15;
    const int qblk = bx >> 5;            // 32 q-blocks of 64 rows
    const int tid  = threadIdx.x;
    const int wave = tid >> 6;
    const int lane = tid & 63;
    const int quad = lane >> 4;
    const int t16  = lane & 15;
    const int team = wave >> 1;          // 0: keys [0,32) of each tile, 1: [32,64)
    const int wv   = wave & 1;           // q-row half within BQ
    const int tb   = team * 32;          // team's key offset within a tile

    // ---- bias LUT with FIXM folded in
    {
        int n = tid;
        int bucket;
        if (n < 16) {
            bucket = n;
        } else {
            int vl = (int)(__log2f((float)n * 0.0625f) * 4.0f);
            bucket = 16 + (vl < 15 ? vl : 15);
        }
        lut[n] = bt[bucket * H_ + h] * LOG2E - FIXM;
    }
    const float sh_next = FIXM - bt[h] * LOG2E;           // all d<=0 (bucket 0)
    const float sh_far  = FIXM - bt[31 * H_ + h] * LOG2E; // all d>=216 (bucket 31)

    // robust event_length read (int32 vs int64 layouts; valid lengths >= 1)
    const int len = (elen[1] == 0) ? elen[2 * b] : elen[b];
    const int ntiles = (len + BK - 1) >> 6;  // keys beyond len give exp()=0 exactly

    const size_t bh = ((size_t)b * H_ + h) * (size_t)(S_ * D_);
    const float* qg = qg_ + bh;
    const float* kg = kg_ + bh;
    const float* vg = vg_ + bh;
    float*       og = outg_ + bh;

    // ---- Q fragments: 2 row-groups (A-layout build, used in B slot -> S^T = K.Q^T)
    half8 qf[2][2];
    #pragma unroll
    for (int rg = 0; rg < 2; ++rg) {
        const float qscale = 0.125f * LOG2E;
        const int row = qblk * BQ + wv * 32 + rg * 16 + t16;
        const float* qp = qg + (size_t)row * D_ + quad * 8;
        #pragma unroll
        for (int c = 0; c < 2; ++c) {
            const float4* p = reinterpret_cast<const float4*>(qp + c * 32);
            float4 x0 = p[0], x1 = p[1];
            half8 hv;
            hv[0] = (_Float16)(x0.x * qscale); hv[1] = (_Float16)(x0.y * qscale);
            hv[2] = (_Float16)(x0.z * qscale); hv[3] = (_Float16)(x0.w * qscale);
            hv[4] = (_Float16)(x1.x * qscale); hv[5] = (_Float16)(x1.y * qscale);
            hv[6] = (_Float16)(x1.z * qscale); hv[7] = (_Float16)(x1.w * qscale);
            qf[rg][c] = hv;
        }
    }

    floatx4 zero4 = {0.f, 0.f, 0.f, 0.f};
    floatx4 acc[2][4];         // acc[rg][nb][r]: qrow rg*16+quad*4+r, dim nb*16+t16
    float l_[2];               // per-lane partial row-sum for qrow rg*16+t16
    #pragma unroll
    for (int rg = 0; rg < 2; ++rg) {
        #pragma unroll
        for (int nb = 0; nb < 4; ++nb) acc[rg][nb] = zero4;
        l_[rg] = 0.f;
    }

    const int i_lo = qblk * BQ + wv * 32;  // first q-row this wave owns

    // ---- software-pipelined staging registers (identical to R5's proven path)
    float4 kx[2][2];
    float  vx[16];
    auto prefetch = [&](int kt) {
        #pragma unroll
        for (int it = 0; it < 2; ++it) {
            int idx = tid + it * 256;
            int row = idx >> 3;
            int c8  = (idx & 7) << 3;
            const float4* p = reinterpret_cast<const float4*>(
                kg + ((size_t)(kt * BK + row) * D_ + c8));
            kx[it][0] = p[0];
            kx[it][1] = p[1];
        }
        #pragma unroll
        for (int it = 0; it < 2; ++it) {
            int key8 = kt * BK + wave * 8 + it * 32;
            #pragma unroll
            for (int jj = 0; jj < 8; ++jj)
                vx[it * 8 + jj] = vg[(size_t)(key8 + jj) * D_ + lane];
        }
    };
    auto stage = [&](int buf) {
        #pragma unroll
        for (int it = 0; it < 2; ++it) {
            int idx = tid + it * 256;
            int row = idx >> 3;
            int c8  = (idx & 7) << 3;
            float4 x0 = kx[it][0], x1 = kx[it][1];
            half8 hv;
            hv[0]=(_Float16)x0.x; hv[1]=(_Float16)x0.y; hv[2]=(_Float16)x0.z; hv[3]=(_Float16)x0.w;
            hv[4]=(_Float16)x1.x; hv[5]=(_Float16)x1.y; hv[6]=(_Float16)x1.z; hv[7]=(_Float16)x1.w;
            *reinterpret_cast<half8*>(&Kl[buf][row][c8]) = hv;
        }
        #pragma unroll
        for (int it = 0; it < 2; ++it) {
            int key8 = wave * 8 + it * 32;
            half8 vv;
            #pragma unroll
            for (int jj = 0; jj < 8; ++jj) vv[jj] = (_Float16)vx[it * 8 + jj];
            *reinterpret_cast<half8*>(&Vt[buf][lane][key8]) = vv;
        }
    };

    prefetch(0);
    stage(0);
    __syncthreads();

    for (int kt = 0; kt < ntiles; ++kt) {
        const int cur = kt & 1;
        const bool more = (kt + 1) < ntiles;
        if (more) prefetch(kt + 1);  // global->regs, hides under compute below

        // ---- S^T for this team's 32 keys: row=key_local (nb*16+quad*4+r), col=q (t16)
        floatx4 sa[2][2];   // [rg][nb]
        #pragma unroll
        for (int rg = 0; rg < 2; ++rg)
            #pragma unroll
            for (int nb = 0; nb < 2; ++nb) sa[rg][nb] = zero4;
        #pragma unroll
        for (int kc = 0; kc < 2; ++kc) {
            #pragma unroll
            for (int nb = 0; nb < 2; ++nb) {
                half8 af = *reinterpret_cast<const half8*>(
                    &Kl[cur][tb + nb * 16 + t16][kc * 32 + quad * 8]);
                sa[0][nb] = __builtin_amdgcn_mfma_f32_16x16x32_f16(af, qf[0][kc], sa[0][nb], 0, 0, 0);
                sa[1][nb] = __builtin_amdgcn_mfma_f32_16x16x32_f16(af, qf[1][kc], sa[1][nb], 0, 0, 0);
            }
        }

        // ---- bias + fixed shift (team-tile spans keys [base, base+32), q [i_lo, +32))
        const int base = kt * BK + tb;
        if (i_lo + 31 <= base) {             // all d <= 0 -> bucket 0
            #pragma unroll
            for (int rg = 0; rg < 2; ++rg)
                #pragma unroll
                for (int nb = 0; nb < 2; ++nb)
                    #pragma unroll
                    for (int r = 0; r < 4; ++r) sa[rg][nb][r] -= sh_next;
        } else if (i_lo >= base + 247) {     // all d >= 216 -> bucket 31
            #pragma unroll
            for (int rg = 0; rg < 2; ++rg)
                #pragma unroll
                for (int nb = 0; nb < 2; ++nb)
                    #pragma unroll
                    for (int r = 0; r < 4; ++r) sa[rg][nb][r] -= sh_far;
        } else {
            #pragma unroll
            for (int rg = 0; rg < 2; ++rg) {
                // d = qrow - key = (i_lo+rg*16+t16) - (base+nb*16+quad*4+r)
                const int d0 = i_lo + rg * 16 + t16 - base - quad * 4;
                #pragma unroll
                for (int nb = 0; nb < 2; ++nb) {
                    #pragma unroll
                    for (int r = 0; r < 4; ++r) {
                        int d = d0 - nb * 16 - r;
                        d = d < 0 ? 0 : (d > 255 ? 255 : d);
                        sa[rg][nb][r] += lut[d];
                    }
                }
            }
        }
        // key-padding mask: only the boundary tile needs it (team may be fully masked)
        if ((kt == ntiles - 1) && (len & 63)) {
            #pragma unroll
            for (int nb = 0; nb < 2; ++nb) {
                #pragma unroll
                for (int r = 0; r < 4; ++r) {
                    bool valid = (base + nb * 16 + quad * 4 + r) < len;
                    #pragma unroll
                    for (int rg = 0; rg < 2; ++rg)
                        sa[rg][nb][r] = valid ? sa[rg][nb][r] : -1e30f;
                }
            }
        }

        // ---- fixed-shift softmax + partial l
        #pragma unroll
        for (int rg = 0; rg < 2; ++rg) {
            float s = 0.f;
            #pragma unroll
            for (int nb = 0; nb < 2; ++nb)
                #pragma unroll
                for (int r = 0; r < 4; ++r) {
                    sa[rg][nb][r] = EXP2F(sa[rg][nb][r]);
                    s += sa[rg][nb][r];
                }
            l_[rg] += s;
        }

        // ---- P: key-contiguous per lane -> 4 packed b64 writes
        #pragma unroll
        for (int rg = 0; rg < 2; ++rg) {
            #pragma unroll
            for (int nb = 0; nb < 2; ++nb) {
                fp16x2 lo = __builtin_amdgcn_cvt_pkrtz(sa[rg][nb][0], sa[rg][nb][1]);
                fp16x2 hi = __builtin_amdgcn_cvt_pkrtz(sa[rg][nb][2], sa[rg][nb][3]);
                half4 w;
                w[0] = (_Float16)lo[0]; w[1] = (_Float16)lo[1];
                w[2] = (_Float16)hi[0]; w[3] = (_Float16)hi[1];
                *reinterpret_cast<half4*>(
                    &Pp[wave][rg * 16 + t16][nb * 16 + quad * 4]) = w;
            }
        }
        asm volatile("s_waitcnt lgkmcnt(0)" ::: "memory");  // own wave's writes visible

        // ---- O += P V over this team's 32 keys (K=32 -> one MFMA step)
        {
            half8 a0 = *reinterpret_cast<const half8*>(&Pp[wave][t16][quad * 8]);
            half8 a1 = *reinterpret_cast<const half8*>(&Pp[wave][16 + t16][quad * 8]);
            #pragma unroll
            for (int nb = 0; nb < 4; ++nb) {
                half8 bv = *reinterpret_cast<const half8*>(
                    &Vt[cur][nb * 16 + t16][tb + quad * 8]);
                acc[0][nb] = __builtin_amdgcn_mfma_f32_16x16x32_f16(a0, bv, acc[0][nb], 0, 0, 0);
                acc[1][nb] = __builtin_amdgcn_mfma_f32_16x16x32_f16(a1, bv, acc[1][nb], 0, 0, 0);
            }
        }

        // ---- stage next tile into the other buffer; one barrier per iteration
        if (more) stage(cur ^ 1);
        __syncthreads();
    }

    // ---- team combine (fixed shift -> plain sums), normalize, store
    float lv[2];
    #pragma unroll
    for (int rg = 0; rg < 2; ++rg) {
        lv[rg] = l_[rg];
        lv[rg] += __shfl_xor(lv[rg], 16, 64);
        lv[rg] += __shfl_xor(lv[rg], 32, 64);   // team row-sum for qrow rg*16+t16
    }
    float* cb = reinterpret_cast<float*>(&Kl[0][0][0]);  // 16KB acc + 256B l (dead dbuf)
    if (team == 1) {
        #pragma unroll
        for (int rg = 0; rg < 2; ++rg) {
            #pragma unroll
            for (int nb = 0; nb < 4; ++nb)
                #pragma unroll
                for (int r = 0; r < 4; ++r)
                    cb[wv * 2048 + (rg * 16 + quad * 4 + r) * 64 + nb * 16 + t16]
                        = acc[rg][nb][r];
            if (quad == 0)
                cb[4096 + wv * 32 + rg * 16 + t16] = lv[rg];
        }
    }
    __syncthreads();
    if (team == 0) {
        #pragma unroll
        for (int rg = 0; rg < 2; ++rg) {
            float ltot = lv[rg] + cb[4096 + wv * 32 + rg * 16 + t16];
            float inv = 1.f / ltot;  // for qrow rg*16+t16, replicated across quads
            #pragma unroll
            for (int r = 0; r < 4; ++r) {
                int rowloc = quad * 4 + r;
                float invr = __shfl(inv, (lane & 48) | rowloc, 64);
                const int row = qblk * BQ + wv * 32 + rg * 16 + rowloc;
                #pragma unroll
                for (int nb = 0; nb < 4; ++nb) {
                    float o = acc[rg][nb][r]
                            + cb[wv * 2048 + (rg * 16 + rowloc) * 64 + nb * 16 + t16];
                    og[(size_t)row * D_ + nb * 16 + t16] = o * invr;
                }
            }
        }
    }
}

extern "C" void kernel_launch(void* const* d_in, const int* in_sizes, int n_in,
                              void* d_out, int out_size, void* d_ws, size_t ws_size,
                              hipStream_t stream) {
    const float* q  = (const float*)d_in[0];
    const float* k  = (const float*)d_in[1];
    const float* v  = (const float*)d_in[2];
    const float* bt = (const float*)d_in[3];
    const int*   el = (const int*)d_in[4];
    float* out = (float*)d_out;
    // 1024 blocks x 256 threads; batch interleaved in bit 0 for load balance
    t5_attn_kernel<<<dim3((S_ / BQ) * H_ * B_), dim3(256), 0, stream>>>(q, k, v, bt, el, out);
}